// Round 1
// baseline (1054.075 us; speedup 1.0000x reference)
//
#include <hip/hip_runtime.h>
#include <hip/hip_bf16.h>
#include <math.h>

#define C_CLASSES 100000
#define D_DIM     128
#define DEPTH     8
#define B_BATCH   2048
#define NBLK_N    782              // ceil(100000/128)
#define C_PAD     (NBLK_N*128)     // 100096
#define NWG_GEMM  (16*NBLK_N)      // 12512, divisible by 8 (XCDs)
#define WG_PER_XCD (NWG_GEMM/8)    // 1564

typedef __bf16 bf16;
typedef __bf16 bf16x4 __attribute__((ext_vector_type(4)));
typedef __bf16 bf16x8 __attribute__((ext_vector_type(8)));
typedef float  f32x4  __attribute__((ext_vector_type(4)));

// ---------------- K0: cast x to bf16 (vectorized, 16B/lane in) ----------------
__global__ __launch_bounds__(256)
void k_cast_x(const float* __restrict__ x, bf16* __restrict__ xb, int n4) {
    int i = blockIdx.x * 256 + threadIdx.x;
    if (i < n4) {
        f32x4 v = ((const f32x4*)x)[i];
        bf16x4 o;
        o[0] = (bf16)v[0]; o[1] = (bf16)v[1]; o[2] = (bf16)v[2]; o[3] = (bf16)v[3];
        ((bf16x4*)xb)[i] = o;
    }
}

// ---------------- K1: gather tree-path rows, sum, cast to bf16 ----------------
// 8 classes per 256-thread block; 32 lanes/class, each lane owns 4 floats (16B loads).
__global__ __launch_bounds__(256)
void k_gather_aw(const float* __restrict__ w, const int* __restrict__ pidx,
                 bf16* __restrict__ aw) {
    int c = blockIdx.x * 8 + (threadIdx.x >> 5);
    int q = threadIdx.x & 31;          // float4 slot within the 128-float row
    if (c >= C_PAD) return;
    f32x4 acc = {0.f, 0.f, 0.f, 0.f};
    if (c < C_CLASSES) {
        const f32x4* wv = (const f32x4*)w;
#pragma unroll
        for (int j = 0; j < DEPTH; ++j) {
            int r = pidx[c * DEPTH + j];
            acc += wv[(size_t)r * 32 + q];
        }
    }
    bf16x4 o;
    o[0] = (bf16)acc[0]; o[1] = (bf16)acc[1]; o[2] = (bf16)acc[2]; o[3] = (bf16)acc[3];
    *(bf16x4*)(aw + (size_t)c * D_DIM + q * 4) = o;    // 8B store, aligned
}

// ---------------- K2: bf16 MFMA GEMM + fused exp-rowsum epilogue ----------------
// logits[m][n] = sum_k xb[m][k] * aw[n][k]   (NT gemm, both operands K-contiguous)
// 128x128 tile / block, 4 waves, each wave 64x64 via 4x4 grid of 16x16x32 frags.
// LDS: 2 x 32KB, XOR swizzle on 16B granules (g' = g ^ (row & 15)) -> <=2-way banks (free).
// Staging via global_load_lds (16B) with PRE-SWIZZLED global source (m173 pattern):
//   linear LDS dest granule idx = m*16 + g'  <-  global granule g'^(m&15) of row m,
// which is byte-identical to the old reg-staged swizzled image.
// XCD-aware chunked remap: the 16 bm-blocks sharing one aw B-tile land on ONE XCD.
__global__ __launch_bounds__(256, 2)
void k_gemm(const bf16* __restrict__ xb, const bf16* __restrict__ aw,
            float* __restrict__ logits, float* __restrict__ partial) {
    __shared__ uint4 As4[128 * 16];   // 32 KB
    __shared__ uint4 Bs4[128 * 16];   // 32 KB
    const int tid = threadIdx.x;

    // bijective XCD swizzle (NWG_GEMM % 8 == 0): hardware round-robins linear id
    // over XCDs, so id%8 is the XCD; give each XCD a contiguous (bm,bn) chunk.
    const int lin = blockIdx.y * 16 + blockIdx.x;
    const int rem = (lin & 7) * WG_PER_XCD + (lin >> 3);
    const int bm = rem & 15, bn = rem >> 4;

    const uint4* xbv = (const uint4*)xb;
    const uint4* awv = (const uint4*)aw;
    const int lane = tid & 63, w = tid >> 6;

    // stage A (x rows) and B (aw rows), full K=128, async direct-to-LDS
#pragma unroll
    for (int it = 0; it < 8; ++it) {
        const int base = it * 256 + w * 64;          // wave-uniform dest granule
        const int idx = base + lane;
        const int m = idx >> 4, gp = idx & 15;
        const int gs = gp ^ (m & 15);                // pre-swizzled source granule
        __builtin_amdgcn_global_load_lds(
            (const __attribute__((address_space(1))) void*)(xbv + (size_t)(bm * 128 + m) * 16 + gs),
            (__attribute__((address_space(3))) void*)(As4 + base),
            16, 0, 0);
    }
#pragma unroll
    for (int it = 0; it < 8; ++it) {
        const int base = it * 256 + w * 64;
        const int idx = base + lane;
        const int m = idx >> 4, gp = idx & 15;
        const int gs = gp ^ (m & 15);
        __builtin_amdgcn_global_load_lds(
            (const __attribute__((address_space(1))) void*)(awv + (size_t)(bn * 128 + m) * 16 + gs),
            (__attribute__((address_space(3))) void*)(Bs4 + base),
            16, 0, 0);
    }
    __syncthreads();   // compiler drains vmcnt before s_barrier

    const int wm = (w >> 1) * 64, wn = (w & 1) * 64;
    const int quad = lane >> 4, l15 = lane & 15;
    const bf16x8* Asv = (const bf16x8*)As4;
    const bf16x8* Bsv = (const bf16x8*)Bs4;

    f32x4 acc[4][4];
#pragma unroll
    for (int ti = 0; ti < 4; ++ti)
#pragma unroll
        for (int tj = 0; tj < 4; ++tj)
            acc[ti][tj] = (f32x4){0.f, 0.f, 0.f, 0.f};

#pragma unroll
    for (int ks = 0; ks < 4; ++ks) {
        const int gsw = (ks * 4 + quad) ^ l15;   // swizzled granule (row&15 == l15)
        bf16x8 af[4], bfr[4];
#pragma unroll
        for (int ti = 0; ti < 4; ++ti) af[ti] = Asv[(wm + ti * 16 + l15) * 16 + gsw];
#pragma unroll
        for (int tj = 0; tj < 4; ++tj) bfr[tj] = Bsv[(wn + tj * 16 + l15) * 16 + gsw];
#pragma unroll
        for (int ti = 0; ti < 4; ++ti)
#pragma unroll
            for (int tj = 0; tj < 4; ++tj)
                acc[ti][tj] = __builtin_amdgcn_mfma_f32_16x16x32_bf16(
                    af[ti], bfr[tj], acc[ti][tj], 0, 0, 0);
    }
    __syncthreads();           // done reading As -> reuse as reduction buffer

    float* red = (float*)As4;  // 256 floats: [2][128] (col-half, row_local)
    red[tid] = 0.f;
    __syncthreads();

    const long col0 = (long)bn * 128 + wn;
    const int  row0 = bm * 128 + wm;
#pragma unroll
    for (int ti = 0; ti < 4; ++ti) {
#pragma unroll
        for (int i = 0; i < 4; ++i) {
            const int row = row0 + ti * 16 + quad * 4 + i;   // C/D: row=(lane>>4)*4+reg
            float rs = 0.f;
#pragma unroll
            for (int tj = 0; tj < 4; ++tj) {
                long col = col0 + tj * 16 + l15;             // C/D: col=lane&15
                float v = acc[ti][tj][i];
                if (col < C_CLASSES) {
                    logits[(long)row * C_CLASSES + col] = v;
                    rs += __expf(v);
                }
            }
            rs += __shfl_xor(rs, 1);
            rs += __shfl_xor(rs, 2);
            rs += __shfl_xor(rs, 4);
            rs += __shfl_xor(rs, 8);
            if (l15 == 0) red[(w & 1) * 128 + wm + ti * 16 + quad * 4 + i] = rs;
        }
    }
    __syncthreads();
    if (tid < 128)
        partial[(size_t)(bm * 128 + tid) * NBLK_N + bn] = red[tid] + red[128 + tid];
}

// ---------------- K3: per-row logsumexp - logit_y ----------------
__global__ __launch_bounds__(256)
void k_row_reduce(const float* __restrict__ partial, const float* __restrict__ logits,
                  const int* __restrict__ y, float* __restrict__ contrib) {
    const int b = blockIdx.x, tid = threadIdx.x;
    float s = 0.f;
    for (int j = tid; j < NBLK_N; j += 256) s += partial[(size_t)b * NBLK_N + j];
#pragma unroll
    for (int m = 1; m < 64; m <<= 1) s += __shfl_xor(s, m);
    __shared__ float sm[4];
    if ((tid & 63) == 0) sm[tid >> 6] = s;
    __syncthreads();
    if (tid == 0) {
        float t = sm[0] + sm[1] + sm[2] + sm[3];
        float lse = logf(t);
        float ly = logits[(size_t)b * C_CLASSES + y[b]];
        contrib[b] = lse - ly;
    }
}

// ---------------- K4: mean over batch -> loss ----------------
__global__ __launch_bounds__(256)
void k_loss(const float* __restrict__ contrib, float* __restrict__ out) {
    const int tid = threadIdx.x;
    float s = 0.f;
#pragma unroll
    for (int k = 0; k < 8; ++k) s += contrib[tid + k * 256];
#pragma unroll
    for (int m = 1; m < 64; m <<= 1) s += __shfl_xor(s, m);
    __shared__ float sm[4];
    if ((tid & 63) == 0) sm[tid >> 6] = s;
    __syncthreads();
    if (tid == 0) out[0] = (sm[0] + sm[1] + sm[2] + sm[3]) * (1.0f / B_BATCH);
}

extern "C" void kernel_launch(void* const* d_in, const int* in_sizes, int n_in,
                              void* d_out, int out_size, void* d_ws, size_t ws_size,
                              hipStream_t stream) {
    const float* x    = (const float*)d_in[0];
    const int*   y    = (const int*)d_in[1];
    const float* w    = (const float*)d_in[2];
    const int*   pidx = (const int*)d_in[3];
    float* out = (float*)d_out;

    // ws layout (16B-aligned offsets)
    char* ws = (char*)d_ws;
    bf16*  xb      = (bf16*)ws;                                   // 2048*128*2     = 512 KB
    bf16*  aw      = (bf16*)(ws + 524288);                        // 100096*128*2   = 25.6 MB
    float* partial = (float*)(ws + 524288 + 25624576);            // 2048*782*4     = 6.4 MB
    float* contrib = (float*)(ws + 524288 + 25624576 + 6406144);  // 2048*4
    float* logits  = out + 1;                                     // d_out[0] = loss

    hipLaunchKernelGGL(k_cast_x, dim3(256), dim3(256), 0, stream, x, xb, B_BATCH * D_DIM / 4);
    hipLaunchKernelGGL(k_gather_aw, dim3(C_PAD / 8), dim3(256), 0, stream, w, pidx, aw);
    hipLaunchKernelGGL(k_gemm, dim3(16, NBLK_N), dim3(256), 0, stream, xb, aw, logits, partial);
    hipLaunchKernelGGL(k_row_reduce, dim3(B_BATCH), dim3(256), 0, stream, partial, logits, y, contrib);
    hipLaunchKernelGGL(k_loss, dim3(1), dim3(256), 0, stream, contrib, out);
}